// Round 1
// baseline (206.486 us; speedup 1.0000x reference)
//
#include <hip/hip_runtime.h>

#define FEAT_D 128
#define TPB 256
#define ROWGROUPS (TPB / 32)   // 8 rows in flight per iteration

__global__ __launch_bounds__(TPB) void seg_mean_kernel(
    const float* __restrict__ feat,   // [N, 128] row-major
    const int* __restrict__ ids,      // [N] sorted segment ids
    float* __restrict__ out,          // [B, 128]
    int N)
{
    const int s = blockIdx.x;

    // --- find [start, end) of segment s via binary search (ids are sorted) ---
    __shared__ int s_bounds[2];
    if (threadIdx.x < 2) {
        const int target = s + (int)threadIdx.x;   // lower_bound(target)
        int lo = 0, hi = N;
        while (lo < hi) {
            int mid = (lo + hi) >> 1;
            if (ids[mid] < target) lo = mid + 1; else hi = mid;
        }
        s_bounds[threadIdx.x] = lo;
    }
    __syncthreads();
    const int start = s_bounds[0];
    const int end   = s_bounds[1];
    const int cnt   = end - start;

    // --- stream the contiguous row range, coalesced float4 loads ---
    const int col4 = threadIdx.x & 31;   // which float4 of the 128-float row
    const int rg   = threadIdx.x >> 5;   // row group 0..7
    const float4* fp = (const float4*)feat;

    float4 acc = make_float4(0.f, 0.f, 0.f, 0.f);
    for (int r = start + rg; r < end; r += ROWGROUPS) {
        float4 v = fp[(size_t)r * 32 + col4];
        acc.x += v.x; acc.y += v.y; acc.z += v.z; acc.w += v.w;
    }

    // --- reduce the 8 row groups ---
    __shared__ float4 red[ROWGROUPS][32];
    red[rg][col4] = acc;
    __syncthreads();

    if (rg == 0) {
        float4 t = red[0][col4];
        #pragma unroll
        for (int g = 1; g < ROWGROUPS; ++g) {
            float4 u = red[g][col4];
            t.x += u.x; t.y += u.y; t.z += u.z; t.w += u.w;
        }
        const float inv = 1.0f / (float)max(cnt, 1);
        t.x *= inv; t.y *= inv; t.z *= inv; t.w *= inv;
        ((float4*)out)[(size_t)s * 32 + col4] = t;
    }
}

extern "C" void kernel_launch(void* const* d_in, const int* in_sizes, int n_in,
                              void* d_out, int out_size, void* d_ws, size_t ws_size,
                              hipStream_t stream) {
    const float* feat = (const float*)d_in[0];
    const int*   ids  = (const int*)d_in[1];
    float*       out  = (float*)d_out;

    const int N = in_sizes[0] / FEAT_D;   // 2,097,152
    const int B = out_size / FEAT_D;      // 8,192 segments

    seg_mean_kernel<<<B, TPB, 0, stream>>>(feat, ids, out, N);
}

// Round 3
// 174.736 us; speedup vs baseline: 1.1817x; 1.1817x over previous
//
#include <hip/hip_runtime.h>

#define FEAT_D 128
#define D4     32          // float4s per row
#define TPB    256
#define NWAVES 4

typedef float f32x4 __attribute__((ext_vector_type(4)));

__global__ __launch_bounds__(TPB) void seg_mean_kernel(
    const float* __restrict__ feat,   // [N, 128] row-major
    const int* __restrict__ ids,      // [N] sorted segment ids
    float* __restrict__ out,          // [B, 128]
    int N)
{
    const int s    = blockIdx.x;
    const int tid  = (int)threadIdx.x;
    const int lane = tid & 63;
    const int wave = tid >> 6;

    // ---- wave-parallel 64-ary lower_bound: wave w searches target s+w ----
    __shared__ int s_bounds[2];
    if (wave < 2) {
        const int target = s + wave;
        int lo = 0, hi = N;   // invariant: ids[<lo] < target, ids[>=hi] >= target
        while (hi - lo > 64) {
            const unsigned span = (unsigned)(hi - lo);
            const int p  = lo + (int)(((unsigned long long)span * (unsigned)lane) >> 6);
            const bool c = (ids[p] < target);
            const unsigned long long m = __ballot(c);
            if (m == 0ull) { hi = lo; break; }           // ids[lo] >= target
            const int h = 63 - __builtin_clzll(m);        // highest true lane
            const int ph  = lo + (int)(((unsigned long long)span * (unsigned)h) >> 6);
            const int ph1 = (h < 63)
                ? lo + (int)(((unsigned long long)span * (unsigned)(h + 1)) >> 6)
                : hi;
            lo = ph + 1;
            hi = ph1;
        }
        // final: linear probe of <=64 candidates
        const int idx = lo + lane;
        const bool c  = (idx < hi) && (ids[idx] < target);
        const int cnt = __popcll(__ballot(c));
        if (lane == 0) s_bounds[wave] = lo + cnt;
    }
    __syncthreads();

    const int start = s_bounds[0];
    const int end   = s_bounds[1];
    const int cnt   = end - start;

    // ---- each wave streams a CONTIGUOUS chunk of rows ----
    const int q    = cnt >> 2;
    const int rem  = cnt & 3;
    const int wbeg = start + q * wave + min(wave, rem);
    const int wcnt = q + (wave < rem ? 1 : 0);
    const int wend = wbeg + wcnt;

    const int rpar = lane >> 5;      // row parity within the wave (0/1)
    const int col4 = lane & 31;      // float4 index within the row
    const f32x4* fp = (const f32x4*)feat + col4;

    f32x4 a0 = (f32x4)(0.f);
    f32x4 a1 = (f32x4)(0.f);

    int r = wbeg + rpar;
    for (; r + 2 < wend; r += 4) {   // rows r and r+2: 2 loads in flight
        const f32x4 v0 = __builtin_nontemporal_load(&fp[(size_t)r       * D4]);
        const f32x4 v1 = __builtin_nontemporal_load(&fp[(size_t)(r + 2) * D4]);
        a0 += v0;
        a1 += v1;
    }
    for (; r < wend; r += 2) {
        a0 += __builtin_nontemporal_load(&fp[(size_t)r * D4]);
    }
    a0 += a1;

    // combine the two row-parities: lane <-> lane^32
    f32x4 o;
    o.x = __shfl_xor(a0.x, 32);
    o.y = __shfl_xor(a0.y, 32);
    o.z = __shfl_xor(a0.z, 32);
    o.w = __shfl_xor(a0.w, 32);
    a0 += o;

    // ---- cross-wave reduce in LDS ----
    __shared__ f32x4 red[NWAVES][D4];
    if ((lane >> 5) == 0) red[wave][col4] = a0;
    __syncthreads();

    if (tid < D4) {
        f32x4 t = red[0][tid];
        #pragma unroll
        for (int g = 1; g < NWAVES; ++g) {
            t += red[g][tid];
        }
        const float inv = 1.0f / (float)max(cnt, 1);
        t *= inv;
        ((f32x4*)out)[(size_t)s * D4 + tid] = t;
    }
}

extern "C" void kernel_launch(void* const* d_in, const int* in_sizes, int n_in,
                              void* d_out, int out_size, void* d_ws, size_t ws_size,
                              hipStream_t stream) {
    const float* feat = (const float*)d_in[0];
    const int*   ids  = (const int*)d_in[1];
    float*       out  = (float*)d_out;

    const int N = in_sizes[0] / FEAT_D;   // 2,097,152
    const int B = out_size / FEAT_D;      // 8,192 segments

    seg_mean_kernel<<<B, TPB, 0, stream>>>(feat, ids, out, N);
}